// Round 1
// baseline (314.197 us; speedup 1.0000x reference)
//
#include <hip/hip_runtime.h>
#include <hip/hip_bf16.h>

// Shapes: input  (8, 256, 256, 64) fp32, NHWC
//         pooled (8,  64,  64, 64) fp32 (in d_ws, 8 MiB)
//         output (8, 256, 256, 64) fp32
// POOL=6, STRIDE=4, SAME padding -> pad_lo = 1 in both spatial dims.

#define B_  8
#define H_  256
#define W_  256
#define C_  64
#define HP  64   // pooled H
#define WP  64   // pooled W

// ---------------- Kernel 1: 6x6 stride-4 SAME avg pool ----------------
// One wave (64 lanes) per pooled pixel; lane = channel. All loads/stores
// are 64 consecutive floats = 256 B coalesced.
__global__ __launch_bounds__(256) void pool_kernel(const float* __restrict__ in,
                                                   float* __restrict__ pooled) {
    int wave = (blockIdx.x * blockDim.x + threadIdx.x) >> 6;
    int lane = threadIdx.x & 63;
    // wave -> (b, i, j) over (B_, HP, WP)
    int j = wave & (WP - 1);
    int i = (wave >> 6) & (HP - 1);
    int b = wave >> 12;

    int rs = i * 4 - 1;           // window row start (may be -1)
    int cs = j * 4 - 1;
    int r0 = rs < 0 ? 0 : rs;
    int c0 = cs < 0 ? 0 : cs;
    int r1 = rs + 6 > H_ ? H_ : rs + 6;
    int c1 = cs + 6 > W_ ? W_ : cs + 6;

    const float* base = in + (size_t)b * H_ * W_ * C_ + lane;
    float sum = 0.0f;
    for (int r = r0; r < r1; ++r) {
        const float* rowp = base + (size_t)r * W_ * C_;
        for (int c = c0; c < c1; ++c) {
            sum += rowp[(size_t)c * C_];
        }
    }
    float cnt = (float)((r1 - r0) * (c1 - c0));
    pooled[(size_t)wave * C_ + lane] = sum / cnt;
}

// ---------------- Kernel 2: "unaverage pool" bilinear upsample ----------------
// dest_to_source with s=4, dsi=2, max_src=63:
//   lo = 5.5, hi = 249.5
//   dest <  lo : src = (dest - 2) / 3.5
//   dest >  hi : src = (dest - 249.5) / 3.5 + 62
//   else       : src = (dest - 1.5) / 4
__device__ __forceinline__ float d2s(float dest) {
    const float s = 4.0f, dsi = 2.0f, maxs = 63.0f;
    float lo = dsi + s - 0.5f;                       // 5.5
    float hi = dsi + (maxs - 1.0f) * s - 0.5f;       // 249.5
    if (dest < lo) {
        return (dest - dsi) / (s - 0.5f);
    } else if (dest > hi) {
        return (dest - dsi + 0.5f - (maxs - 1.0f) * s) / (s - 0.5f) + maxs - 1.0f;
    } else {
        return (dest - dsi + 0.5f) / s;
    }
}

__global__ __launch_bounds__(256) void upsample_kernel(const float* __restrict__ pooled,
                                                       float* __restrict__ out) {
    int wave = (blockIdx.x * blockDim.x + threadIdx.x) >> 6;
    int lane = threadIdx.x & 63;
    // wave -> (b, hd, wd) over (B_, H_, W_)
    int wd = wave & (W_ - 1);
    int hd = (wave >> 8) & (H_ - 1);
    int b  = wave >> 16;

    float sr = d2s((float)hd);
    float sc = d2s((float)wd);
    float r0f = floorf(sr), c0f = floorf(sc);
    int r0 = (int)r0f, c0 = (int)c0f;
    float fr = sr - r0f;
    float fc = sc - c0f;

    const float* pb = pooled + (size_t)b * HP * WP * C_ + lane;

    // out-of-range taps contribute 0 (reference clips index then masks)
    float p00 = 0.0f, p01 = 0.0f, p10 = 0.0f, p11 = 0.0f;
    bool rv0 = (r0 >= 0) & (r0 < HP);
    bool rv1 = (r0 + 1 >= 0) & (r0 + 1 < HP);
    bool cv0 = (c0 >= 0) & (c0 < WP);
    bool cv1 = (c0 + 1 >= 0) & (c0 + 1 < WP);
    if (rv0 & cv0) p00 = pb[((size_t)r0 * WP + c0) * C_];
    if (rv0 & cv1) p01 = pb[((size_t)r0 * WP + (c0 + 1)) * C_];
    if (rv1 & cv0) p10 = pb[((size_t)(r0 + 1) * WP + c0) * C_];
    if (rv1 & cv1) p11 = pb[((size_t)(r0 + 1) * WP + (c0 + 1)) * C_];

    float v = p00 * (1.0f - fr) * (1.0f - fc)
            + p01 * (1.0f - fr) * fc
            + p10 * fr * (1.0f - fc)
            + p11 * fr * fc;

    out[(size_t)wave * C_ + lane] = v;
}

extern "C" void kernel_launch(void* const* d_in, const int* in_sizes, int n_in,
                              void* d_out, int out_size, void* d_ws, size_t ws_size,
                              hipStream_t stream) {
    const float* in  = (const float*)d_in[0];
    float* out       = (float*)d_out;
    float* pooled    = (float*)d_ws;   // 8*64*64*64*4 B = 8 MiB

    // Kernel 1: 8*64*64 = 32768 waves, 4 waves/block -> 8192 blocks
    {
        int waves = B_ * HP * WP;
        dim3 grid(waves / 4), block(256);
        pool_kernel<<<grid, block, 0, stream>>>(in, pooled);
    }
    // Kernel 2: 8*256*256 = 524288 waves -> 131072 blocks
    {
        int waves = B_ * H_ * W_;
        dim3 grid(waves / 4), block(256);
        upsample_kernel<<<grid, block, 0, stream>>>(pooled, out);
    }
}

// Round 2
// 248.498 us; speedup vs baseline: 1.2644x; 1.2644x over previous
//
#include <hip/hip_runtime.h>
#include <hip/hip_bf16.h>

// Shapes: input  (8, 256, 256, 64) fp32, NHWC
//         pooled (8,  64,  64, 64) fp32 (in d_ws, 8 MiB)
//         output (8, 256, 256, 64) fp32
// POOL=6, STRIDE=4, SAME padding -> pad_lo = 1 in both spatial dims.
//
// R1: float4-per-thread (4 channels, 16 threads/pixel) + fully-unrolled
// interior fast path. R0 was latency-bound (VGPR=8, 1.1 TB/s).

#define B_  8
#define H_  256
#define W_  256
#define C_  64
#define HP  64
#define WP  64
#define CG  16            // float4 channel groups per pixel
#define RS4 (W_ * C_ / 4) // row stride in float4 units = 4096
#define CS4 (C_ / 4)      // col stride in float4 units = 16

__device__ __forceinline__ float4 f4add(float4 a, float4 b) {
    return make_float4(a.x + b.x, a.y + b.y, a.z + b.z, a.w + b.w);
}

// ---------------- Kernel 1: 6x6 stride-4 SAME avg pool ----------------
__global__ __launch_bounds__(256) void pool_kernel(const float* __restrict__ in,
                                                   float* __restrict__ pooled) {
    int gid = blockIdx.x * blockDim.x + threadIdx.x;
    int cg = gid & (CG - 1);
    int j  = (gid >> 4) & (WP - 1);
    int i  = (gid >> 10) & (HP - 1);
    int b  = gid >> 16;

    int rs = i * 4 - 1;
    int cs = j * 4 - 1;

    float4 sum = make_float4(0.f, 0.f, 0.f, 0.f);
    float scale;

    bool interior = (unsigned)(i - 1) < 62u && (unsigned)(j - 1) < 62u;
    if (interior) {
        const float4* p = (const float4*)(in + (((size_t)b * H_ + rs) * W_ + cs) * C_) + cg;
        #pragma unroll
        for (int r = 0; r < 6; ++r) {
            #pragma unroll
            for (int c = 0; c < 6; ++c) {
                sum = f4add(sum, p[r * RS4 + c * CS4]);
            }
        }
        scale = 1.0f / 36.0f;
    } else {
        int r0 = rs < 0 ? 0 : rs;
        int c0 = cs < 0 ? 0 : cs;
        int r1 = rs + 6 > H_ ? H_ : rs + 6;
        int c1 = cs + 6 > W_ ? W_ : cs + 6;
        const float4* base = (const float4*)(in + (size_t)b * H_ * W_ * C_) + cg;
        for (int r = r0; r < r1; ++r) {
            #pragma unroll 6
            for (int c = c0; c < c1; ++c) {
                sum = f4add(sum, base[(size_t)r * RS4 + (size_t)c * CS4]);
            }
        }
        scale = 1.0f / (float)((r1 - r0) * (c1 - c0));
    }

    float4 v = make_float4(sum.x * scale, sum.y * scale, sum.z * scale, sum.w * scale);
    ((float4*)pooled)[gid] = v;
}

// ---------------- Kernel 2: "unaverage pool" bilinear upsample ----------------
// dest_to_source with s=4, dsi=2, max_src=63: lo=5.5, hi=249.5
__device__ __forceinline__ float d2s(float dest) {
    const float s = 4.0f, dsi = 2.0f, maxs = 63.0f;
    float lo = dsi + s - 0.5f;                       // 5.5
    float hi = dsi + (maxs - 1.0f) * s - 0.5f;       // 249.5
    if (dest < lo) {
        return (dest - dsi) / (s - 0.5f);
    } else if (dest > hi) {
        return (dest - dsi + 0.5f - (maxs - 1.0f) * s) / (s - 0.5f) + maxs - 1.0f;
    } else {
        return (dest - dsi + 0.5f) / s;
    }
}

__global__ __launch_bounds__(256) void upsample_kernel(const float* __restrict__ pooled,
                                                       float* __restrict__ out) {
    int gid = blockIdx.x * blockDim.x + threadIdx.x;
    int cg = gid & (CG - 1);
    int wd = (gid >> 4) & (W_ - 1);
    int hd = (gid >> 12) & (H_ - 1);
    int b  = gid >> 20;

    float sr = d2s((float)hd);
    float sc = d2s((float)wd);
    float r0f = floorf(sr), c0f = floorf(sc);
    int r0 = (int)r0f, c0 = (int)c0f;
    float fr = sr - r0f;
    float fc = sc - c0f;

    const float4* pb = (const float4*)(pooled + (size_t)b * HP * WP * C_) + cg;

    float4 z = make_float4(0.f, 0.f, 0.f, 0.f);
    float4 p00 = z, p01 = z, p10 = z, p11 = z;
    bool rv0 = (unsigned)r0 < (unsigned)HP;
    bool rv1 = (unsigned)(r0 + 1) < (unsigned)HP;
    bool cv0 = (unsigned)c0 < (unsigned)WP;
    bool cv1 = (unsigned)(c0 + 1) < (unsigned)WP;
    if (rv0 & cv0) p00 = pb[((size_t)r0 * WP + c0) * CS4];
    if (rv0 & cv1) p01 = pb[((size_t)r0 * WP + (c0 + 1)) * CS4];
    if (rv1 & cv0) p10 = pb[((size_t)(r0 + 1) * WP + c0) * CS4];
    if (rv1 & cv1) p11 = pb[((size_t)(r0 + 1) * WP + (c0 + 1)) * CS4];

    float w00 = (1.0f - fr) * (1.0f - fc);
    float w01 = (1.0f - fr) * fc;
    float w10 = fr * (1.0f - fc);
    float w11 = fr * fc;

    float4 v;
    v.x = p00.x * w00 + p01.x * w01 + p10.x * w10 + p11.x * w11;
    v.y = p00.y * w00 + p01.y * w01 + p10.y * w10 + p11.y * w11;
    v.z = p00.z * w00 + p01.z * w01 + p10.z * w10 + p11.z * w11;
    v.w = p00.w * w00 + p01.w * w01 + p10.w * w10 + p11.w * w11;

    ((float4*)out)[gid] = v;
}

extern "C" void kernel_launch(void* const* d_in, const int* in_sizes, int n_in,
                              void* d_out, int out_size, void* d_ws, size_t ws_size,
                              hipStream_t stream) {
    const float* in  = (const float*)d_in[0];
    float* out       = (float*)d_out;
    float* pooled    = (float*)d_ws;   // 8 MiB

    // Kernel 1: 8*64*64*16 threads = 524288 -> 2048 blocks
    pool_kernel<<<dim3(B_ * HP * WP * CG / 256), dim3(256), 0, stream>>>(in, pooled);
    // Kernel 2: 8*256*256*16 threads = 8388608 -> 32768 blocks
    upsample_kernel<<<dim3(B_ * H_ * W_ * CG / 256), dim3(256), 0, stream>>>(pooled, out);
}